// Round 13
// baseline (92.751 us; speedup 1.0000x reference)
//
#include <hip/hip_runtime.h>

// ---------- types & helpers ----------
typedef __attribute__((ext_vector_type(8))) short bf16x8;
typedef __attribute__((ext_vector_type(4))) float f32x4;
typedef __attribute__((ext_vector_type(4))) unsigned u32x4;

__device__ inline unsigned short f2bf(float f) {
  unsigned u = __builtin_bit_cast(unsigned, f);
  unsigned r = u + 0x7FFFu + ((u >> 16) & 1u);
  return (unsigned short)(r >> 16);
}
__device__ inline float bf2f(unsigned short s) {
  unsigned u = ((unsigned)s) << 16;
  return __builtin_bit_cast(float, u);
}
__device__ inline float fexp2(float x) { return __builtin_amdgcn_exp2f(x); }

__device__ inline void gload_lds16(const unsigned short* g, unsigned short* l) {
  __builtin_amdgcn_global_load_lds(
      (const __attribute__((address_space(1))) unsigned int*)g,
      (__attribute__((address_space(3))) unsigned int*)l, 16, 0, 0);
}

// PV key-permutation: key kappa (within 64-tile) -> slot k'
__device__ __host__ inline int pv_perm(int k) {
  return ((k >> 5) & 1) * 32 + ((k >> 2) & 3) * 8 + ((k >> 4) & 1) * 4 + (k & 3);
}

// ---------- fused preprocessing: x->bf16, 4 weight transposes, mask bias + tileok ----------
__global__ __launch_bounds__(256) void prep_kernel(
    const float* __restrict__ x, const int* __restrict__ mask,
    const float* __restrict__ w_q, const float* __restrict__ w_d,
    const float* __restrict__ w_k, const float* __restrict__ w_v,
    unsigned short* __restrict__ x_bf, unsigned short* __restrict__ wqdt,
    unsigned short* __restrict__ wkvt, float* __restrict__ bias,
    int* __restrict__ tileok) {
  int bid = blockIdx.x;
  if (bid < 1024) {  // x fp32 -> bf16
    int base = bid * 4096 + threadIdx.x * 4;
#pragma unroll
    for (int it = 0; it < 4; ++it) {
      int idx = base + it * 1024;
      float4 v = *(const float4*)&x[idx];
      ushort4 o;
      o.x = f2bf(v.x); o.y = f2bf(v.y); o.z = f2bf(v.z); o.w = f2bf(v.w);
      *(ushort4*)&x_bf[idx] = o;
    }
    return;
  }
  int tb = bid - 1024;
  if (tb >= 1408) {  // mask -> additive bias + per-64-key-tile all-valid flag
    int i = (tb - 1408) * 256 + threadIdx.x;
    int mv = mask[i];
    bias[i] = mv ? 0.0f : -1e30f;
    int ok = __all(mv != 0);
    if ((threadIdx.x & 63) == 0) tileok[i >> 6] = ok;
    return;
  }
  const float* in; unsigned short* out; int R, C, tr, tc;
  if (tb < 1024)      { in = w_q; out = wqdt;               R = 1024; C = 1024; tr = tb >> 5; tc = tb & 31; }
  else if (tb < 1152) { int t2 = tb - 1024; in = w_d; out = wqdt + 1024 * 1024; R = 1024; C = 128; tr = t2 >> 2; tc = t2 & 3; }
  else if (tb < 1280) { int t2 = tb - 1152; in = w_k; out = wkvt;               R = 128; C = 1024; tr = t2 >> 5; tc = t2 & 31; }
  else                { int t2 = tb - 1280; in = w_v; out = wkvt + 1024 * 128;  R = 128; C = 1024; tr = t2 >> 5; tc = t2 & 31; }
  __shared__ float t[32][33];
  int r0 = tr * 32, c0 = tc * 32;
  int tx = threadIdx.x & 31, ty = threadIdx.x >> 5;
  for (int r = ty; r < 32; r += 8)
    t[r][tx] = in[(size_t)(r0 + r) * C + c0 + tx];
  __syncthreads();
  for (int cc = ty; cc < 32; cc += 8)
    out[(size_t)(c0 + cc) * R + r0 + tx] = f2bf(t[tx][cc]);
}

// ---------- GEMM: C[M][N] = A[M][K] * Bt[N][K]^T ----------
template <int BN>
__global__ __launch_bounds__(256) void gemm_bt(const unsigned short* __restrict__ A, int lda,
                                               const unsigned short* __restrict__ Bt, int ldb,
                                               unsigned short* __restrict__ C, int ldc,
                                               int K) {
  constexpr int WM = (BN == 128) ? 2 : 4;
  constexpr int WN = 4 / WM;
  constexpr int MR = 128 / WM / 16;
  constexpr int NR = BN / WN / 16;
  constexpr int RPW = 128 / WM;
  constexpr int CPW = BN / WN;
  __shared__ unsigned short As[128 * 32];
  __shared__ unsigned short Bs[BN * 32];
  int m0 = blockIdx.x * 128, n0 = blockIdx.y * BN;
  int tid = threadIdx.x, w = tid >> 6, l = tid & 63;
  int lr = l & 15, lg = l >> 4;
  int wr = w / WN, wc = w % WN;
  f32x4 acc[MR][NR] = {};

  for (int k0 = 0; k0 < K; k0 += 32) {
    __syncthreads();
#pragma unroll
    for (int it = 0; it < 2; ++it) {
      int c = w * 2 + it;
      int row = c * 16 + (l >> 2);
      int col = (l & 3) * 8;
      gload_lds16(&A[(size_t)(m0 + row) * lda + k0 + col], &As[c * 512 + l * 8]);
    }
    if constexpr (BN == 128) {
#pragma unroll
      for (int it = 0; it < 2; ++it) {
        int c = w * 2 + it;
        int row = c * 16 + (l >> 2);
        int col = (l & 3) * 8;
        gload_lds16(&Bt[(size_t)(n0 + row) * ldb + k0 + col], &Bs[c * 512 + l * 8]);
      }
    } else {
      int row = w * 16 + (l >> 2);
      int col = (l & 3) * 8;
      gload_lds16(&Bt[(size_t)(n0 + row) * ldb + k0 + col], &Bs[w * 512 + l * 8]);
    }
    __syncthreads();
    bf16x8 af[MR], bfr[NR];
#pragma unroll
    for (int m = 0; m < MR; ++m)
      af[m] = *(const bf16x8*)&As[(wr * RPW + m * 16 + lr) * 32 + lg * 8];
#pragma unroll
    for (int n = 0; n < NR; ++n)
      bfr[n] = *(const bf16x8*)&Bs[(wc * CPW + n * 16 + lr) * 32 + lg * 8];
    __builtin_amdgcn_s_setprio(1);
#pragma unroll
    for (int m = 0; m < MR; ++m)
#pragma unroll
      for (int n = 0; n < NR; ++n)
        acc[m][n] = __builtin_amdgcn_mfma_f32_16x16x32_bf16(af[m], bfr[n], acc[m][n], 0, 0, 0);
    __builtin_amdgcn_s_setprio(0);
  }

#pragma unroll
  for (int m = 0; m < MR; ++m)
#pragma unroll
    for (int n = 0; n < NR; ++n)
#pragma unroll
      for (int i = 0; i < 4; ++i)
        C[(size_t)(m0 + wr * RPW + m * 16 + lg * 4 + i) * ldc + n0 + wc * CPW + n * 16 + lr] =
            f2bf(acc[m][n][i]);
}

// ---------- gemm2 with fused V transpose+permute epilogue ----------
__global__ __launch_bounds__(256) void gemm_kv(const unsigned short* __restrict__ A,
                                               const unsigned short* __restrict__ Bt,
                                               unsigned short* __restrict__ kvK,
                                               unsigned short* __restrict__ vt) {
  __shared__ unsigned short As[128 * 32];
  __shared__ unsigned short Bs[128 * 32];
  int m0 = blockIdx.x * 128, n0 = blockIdx.y * 128;
  int tid = threadIdx.x, w = tid >> 6, l = tid & 63;
  int lr = l & 15, lg = l >> 4;
  int wr = w >> 1, wc = w & 1;
  f32x4 acc[4][4] = {};

  for (int k0 = 0; k0 < 128; k0 += 32) {
    __syncthreads();
#pragma unroll
    for (int it = 0; it < 2; ++it) {
      int c = w * 2 + it;
      int row = c * 16 + (l >> 2);
      int col = (l & 3) * 8;
      gload_lds16(&A[(size_t)(m0 + row) * 1152 + k0 + col], &As[c * 512 + l * 8]);
      gload_lds16(&Bt[(size_t)(n0 + row) * 128 + k0 + col], &Bs[c * 512 + l * 8]);
    }
    __syncthreads();
    bf16x8 af[4], bfr[4];
#pragma unroll
    for (int m = 0; m < 4; ++m)
      af[m] = *(const bf16x8*)&As[(wr * 64 + m * 16 + lr) * 32 + lg * 8];
#pragma unroll
    for (int n = 0; n < 4; ++n)
      bfr[n] = *(const bf16x8*)&Bs[(wc * 64 + n * 16 + lr) * 32 + lg * 8];
    __builtin_amdgcn_s_setprio(1);
#pragma unroll
    for (int m = 0; m < 4; ++m)
#pragma unroll
      for (int n = 0; n < 4; ++n)
        acc[m][n] = __builtin_amdgcn_mfma_f32_16x16x32_bf16(af[m], bfr[n], acc[m][n], 0, 0, 0);
    __builtin_amdgcn_s_setprio(0);
  }

  if (blockIdx.y < 8) {  // K half
#pragma unroll
    for (int m = 0; m < 4; ++m)
#pragma unroll
      for (int n = 0; n < 4; ++n)
#pragma unroll
        for (int i = 0; i < 4; ++i)
          kvK[(size_t)(m0 + wr * 64 + m * 16 + lg * 4 + i) * 2048 + n0 + wc * 64 + n * 16 + lr] =
              f2bf(acc[m][n][i]);
  } else {  // V half: transposed + pv_perm'd
#pragma unroll
    for (int m = 0; m < 4; ++m)
#pragma unroll
      for (int n = 0; n < 4; ++n) {
        int vc = n0 - 1024 + wc * 64 + n * 16 + lr;
        int hh = vc >> 6, dd = vc & 63;
        int row0 = m0 + wr * 64 + m * 16 + lg * 4;
        int bb = row0 >> 11, t0 = row0 & 2047;
        size_t vrow = (size_t)((bb * 16 + hh) * 64 + dd);
        int slot = (t0 >> 6) * 64 + pv_perm(t0 & 63);
        ushort4 o;
        o.x = f2bf(acc[m][n][0]); o.y = f2bf(acc[m][n][1]);
        o.z = f2bf(acc[m][n][2]); o.w = f2bf(acc[m][n][3]);
        *(ushort4*)&vt[vrow * 2048 + slot] = o;
      }
  }
}

// ---------- flash attention: 1 wave/block, 32 q-rows, barrier-free LDS ----------
// grid (bh=32, y=64), qt32 = 63 - y (heaviest first). Single wave owns rows
// qt32*32 + qb*16 + lr (qb=0,1). 64-key tiles; nkv = qt32/2 + 1. No __syncthreads:
// in-wave LDS RAW ordered by lgkmcnt.
__global__ __launch_bounds__(64, 2) void attn_kernel(const unsigned short* __restrict__ qg,
                                                     const unsigned short* __restrict__ kvg,
                                                     const unsigned short* __restrict__ vtg,
                                                     const float* __restrict__ biasg,
                                                     const int* __restrict__ tileokg,
                                                     float* __restrict__ outg) {
  const int bh = blockIdx.x, qt32 = 63 - blockIdx.y;
  const int b = bh >> 4, h = bh & 15;
  const int l = threadIdx.x & 63, lr = l & 15, lg = l >> 4;

  __shared__ unsigned short Ks[64 * 72];  // [key][d]
  __shared__ unsigned short Vs[64 * 72];  // [d][permuted key]

  const int qrow0 = qt32 * 32;
  const int nkv = (qt32 >> 1) + 1;
  const int dov0 = (qt32 & 1) * 32 + lr;  // causal limit qb=0; +16 for qb=1
  const float QSCALE = 0.125f * 1.44269504089f;

  // Q fragments, two 16-row column blocks
  bf16x8 qf[2][2];
#pragma unroll
  for (int qb = 0; qb < 2; ++qb)
#pragma unroll
    for (int ks = 0; ks < 2; ++ks) {
      bf16x8 raw = *(const bf16x8*)&qg[(size_t)(b * 2048 + qrow0 + qb * 16 + lr) * 1152 +
                                       h * 64 + ks * 32 + lg * 8];
#pragma unroll
      for (int j = 0; j < 8; ++j)
        raw[j] = (short)f2bf(bf2f((unsigned short)raw[j]) * QSCALE);
      qf[qb][ks] = raw;
    }

  f32x4 acc[4][2] = {};            // [dt][qb]
  float m_i[2] = {-1e30f, -1e30f};
  float l_part[2] = {0.f, 0.f};

  // prologue: stage tile 0 (64 threads -> 8 chunks per tensor, coalesced 1KB/instr)
  bf16x8 kreg[8], vreg[8];
#pragma unroll
  for (int it = 0; it < 8; ++it) {
    int row = it * 8 + (l >> 3), c8 = (l & 7) * 8;
    kreg[it] = *(const bf16x8*)&kvg[(size_t)(b * 2048 + row) * 2048 + h * 64 + c8];
    vreg[it] = *(const bf16x8*)&vtg[((size_t)(bh * 64 + row)) * 2048 + c8];
  }
#pragma unroll
  for (int it = 0; it < 8; ++it) {
    int row = it * 8 + (l >> 3), c8 = (l & 7) * 8;
    *(bf16x8*)&Ks[row * 72 + c8] = kreg[it];
    *(bf16x8*)&Vs[row * 72 + c8] = vreg[it];
  }
  asm volatile("s_waitcnt lgkmcnt(0)" ::: "memory");
  __builtin_amdgcn_sched_barrier(0);

  for (int kt = 0; kt < nkv; ++kt) {
    // T14 async-stage: issue next tile's global loads now; ds_write after PV
    if (kt + 1 < nkv) {
#pragma unroll
      for (int it = 0; it < 8; ++it) {
        int row = it * 8 + (l >> 3), c8 = (l & 7) * 8;
        kreg[it] = *(const bf16x8*)&kvg[(size_t)(b * 2048 + (kt + 1) * 64 + row) * 2048 + h * 64 + c8];
        vreg[it] = *(const bf16x8*)&vtg[((size_t)(bh * 64 + row)) * 2048 + (kt + 1) * 64 + c8];
      }
    }

    // S^T = K Q^T: K-frag loaded once per (n,ks), reused for both qb
    f32x4 s[2][4];
    __builtin_amdgcn_s_setprio(1);
#pragma unroll
    for (int n = 0; n < 4; ++n) {
      bf16x8 kf0 = *(const bf16x8*)&Ks[(n * 16 + lr) * 72 + lg * 8];
      bf16x8 kf1 = *(const bf16x8*)&Ks[(n * 16 + lr) * 72 + 32 + lg * 8];
#pragma unroll
      for (int qb = 0; qb < 2; ++qb) {
        f32x4 z = {};
        z = __builtin_amdgcn_mfma_f32_16x16x32_bf16(kf0, qf[qb][0], z, 0, 0, 0);
        z = __builtin_amdgcn_mfma_f32_16x16x32_bf16(kf1, qf[qb][1], z, 0, 0, 0);
        s[qb][n] = z;
      }
    }
    __builtin_amdgcn_s_setprio(0);

    const int tok = tileokg[b * 32 + kt];
    const bool diag = (kt == nkv - 1);
    float mx[2] = {-1e30f, -1e30f};
    if (tok) {
      if (diag) {
#pragma unroll
        for (int qb = 0; qb < 2; ++qb)
#pragma unroll
          for (int n = 0; n < 4; ++n)
#pragma unroll
            for (int i = 0; i < 4; ++i) {
              int keyl = n * 16 + lg * 4 + i;
              float v = (keyl <= dov0 + qb * 16) ? s[qb][n][i] : -1e30f;
              s[qb][n][i] = v;
              mx[qb] = fmaxf(mx[qb], v);
            }
      } else {
#pragma unroll
        for (int qb = 0; qb < 2; ++qb)
#pragma unroll
          for (int n = 0; n < 4; ++n)
#pragma unroll
            for (int i = 0; i < 4; ++i)
              mx[qb] = fmaxf(mx[qb], s[qb][n][i]);
      }
    } else {  // rare general-mask path
#pragma unroll
      for (int n = 0; n < 4; ++n)
#pragma unroll
        for (int i = 0; i < 4; ++i) {
          int keyl = n * 16 + lg * 4 + i;
          float bsv = biasg[b * 2048 + kt * 64 + keyl];
#pragma unroll
          for (int qb = 0; qb < 2; ++qb) {
            float v = s[qb][n][i] + bsv;
            if (diag) v = (keyl <= dov0 + qb * 16) ? v : -1e30f;
            s[qb][n][i] = v;
            mx[qb] = fmaxf(mx[qb], v);
          }
        }
    }
#pragma unroll
    for (int qb = 0; qb < 2; ++qb) {
      mx[qb] = fmaxf(mx[qb], __shfl_xor(mx[qb], 16, 64));
      mx[qb] = fmaxf(mx[qb], __shfl_xor(mx[qb], 32, 64));
    }

    // T13 defer-rescale (THR=8 in log2 domain)
    float g = fmaxf(mx[0] - m_i[0], mx[1] - m_i[1]);
    if (__any(g > 8.0f)) {
#pragma unroll
      for (int qb = 0; qb < 2; ++qb) {
        float mn = fmaxf(m_i[qb], mx[qb]);
        float sc = fexp2(m_i[qb] - mn);
        m_i[qb] = mn;
        l_part[qb] *= sc;
        float scb[4];
#pragma unroll
        for (int i = 0; i < 4; ++i) scb[i] = __shfl(sc, lg * 4 + i, 64);
#pragma unroll
        for (int dt = 0; dt < 4; ++dt)
#pragma unroll
          for (int i = 0; i < 4; ++i) acc[dt][qb][i] *= scb[i];
      }
    }

#pragma unroll
    for (int qb = 0; qb < 2; ++qb) {
      float rs = 0.f;
#pragma unroll
      for (int n = 0; n < 4; ++n)
#pragma unroll
        for (int i = 0; i < 4; ++i) {
          float e = fexp2(s[qb][n][i] - m_i[qb]);
          s[qb][n][i] = e;
          rs += e;
        }
      l_part[qb] += rs;
    }

    // P -> PV A-fragments in registers (V pre-permuted by pv_perm)
    bf16x8 paf[2][2];
#pragma unroll
    for (int qb = 0; qb < 2; ++qb)
#pragma unroll
      for (int ks = 0; ks < 2; ++ks) {
        unsigned t0, t1, t2, t3;
        asm("v_cvt_pk_bf16_f32 %0, %1, %2" : "=v"(t0) : "v"(s[qb][2 * ks][0]), "v"(s[qb][2 * ks][1]));
        asm("v_cvt_pk_bf16_f32 %0, %1, %2" : "=v"(t1) : "v"(s[qb][2 * ks][2]), "v"(s[qb][2 * ks][3]));
        asm("v_cvt_pk_bf16_f32 %0, %1, %2" : "=v"(t2) : "v"(s[qb][2 * ks + 1][0]), "v"(s[qb][2 * ks + 1][1]));
        asm("v_cvt_pk_bf16_f32 %0, %1, %2" : "=v"(t3) : "v"(s[qb][2 * ks + 1][2]), "v"(s[qb][2 * ks + 1][3]));
        u32x4 uv;
        uv[0] = t0; uv[1] = t1; uv[2] = t2; uv[3] = t3;
        paf[qb][ks] = __builtin_bit_cast(bf16x8, uv);
      }

    // O += P V: V-frag loaded once per (dt,ks), reused for both qb
    __builtin_amdgcn_s_setprio(1);
#pragma unroll
    for (int ks = 0; ks < 2; ++ks)
#pragma unroll
      for (int dt = 0; dt < 4; ++dt) {
        bf16x8 vf = *(const bf16x8*)&Vs[(dt * 16 + lr) * 72 + ks * 32 + lg * 8];
#pragma unroll
        for (int qb = 0; qb < 2; ++qb)
          acc[dt][qb] = __builtin_amdgcn_mfma_f32_16x16x32_bf16(paf[qb][ks], vf, acc[dt][qb], 0, 0, 0);
      }
    __builtin_amdgcn_s_setprio(0);

    // write next tile into LDS (in-wave ordering: lgkmcnt fences RAW, no barrier)
    if (kt + 1 < nkv) {
#pragma unroll
      for (int it = 0; it < 8; ++it) {
        int row = it * 8 + (l >> 3), c8 = (l & 7) * 8;
        *(bf16x8*)&Ks[row * 72 + c8] = kreg[it];
        *(bf16x8*)&Vs[row * 72 + c8] = vreg[it];
      }
      asm volatile("s_waitcnt lgkmcnt(0)" ::: "memory");
      __builtin_amdgcn_sched_barrier(0);
    }
  }

  // epilogue: finish l reduction, normalize, store
#pragma unroll
  for (int qb = 0; qb < 2; ++qb) {
    float lt = l_part[qb];
    lt += __shfl_xor(lt, 16, 64);
    lt += __shfl_xor(lt, 32, 64);
    float inv = 1.f / lt;
    float invb[4];
#pragma unroll
    for (int i = 0; i < 4; ++i) invb[i] = __shfl(inv, lg * 4 + i, 64);
#pragma unroll
    for (int dt = 0; dt < 4; ++dt)
#pragma unroll
      for (int i = 0; i < 4; ++i)
        outg[(size_t)(b * 2048 + qrow0 + qb * 16 + lg * 4 + i) * 1024 + h * 64 + dt * 16 + lr] =
            acc[dt][qb][i] * invb[i];
  }
}

// ---------- launch ----------
extern "C" void kernel_launch(void* const* d_in, const int* in_sizes, int n_in,
                              void* d_out, int out_size, void* d_ws, size_t ws_size,
                              hipStream_t stream) {
  const float* x    = (const float*)d_in[0];
  const int*   mask = (const int*)d_in[1];
  const float* w_q  = (const float*)d_in[2];
  const float* w_d  = (const float*)d_in[3];
  const float* w_k  = (const float*)d_in[4];
  const float* w_v  = (const float*)d_in[5];
  float* out = (float*)d_out;

  char* ws = (char*)d_ws;
  size_t off = 0;
  auto alloc = [&](size_t elems) {
    unsigned short* p = (unsigned short*)(ws + off);
    off += ((elems * 2 + 255) & ~(size_t)255);
    return p;
  };
  unsigned short* x_bf = alloc(4194304);      // [4096][1024]
  unsigned short* wqdt = alloc(1152 * 1024);  // [1152][1024]
  unsigned short* wkvt = alloc(2048 * 128);   // [2048][128]
  unsigned short* qlat = alloc(4096 * 1152);  // [4096][1152]: q | latent
  unsigned short* kv   = alloc(4096 * 2048);  // [4096][2048]: K in cols 0..1023
  unsigned short* vt   = alloc(4194304);      // [32][64][2048], pv_perm'd
  float* bias = (float*)alloc(8192);          // 4096 floats
  int* tileok = (int*)alloc(128);             // 64 ints

  prep_kernel<<<2448, 256, 0, stream>>>(x, mask, w_q, w_d, w_k, w_v, x_bf, wqdt, wkvt, bias, tileok);

  gemm_bt<64><<<dim3(32, 18), 256, 0, stream>>>(x_bf, 1024, wqdt, 1024, qlat, 1152, 1024);
  gemm_kv<<<dim3(32, 16), 256, 0, stream>>>(qlat + 1024, wkvt, kv, vt);

  attn_kernel<<<dim3(32, 64), 64, 0, stream>>>(qlat, kv, vt, bias, tileok, out);
}

// Round 14
// 84.229 us; speedup vs baseline: 1.1012x; 1.1012x over previous
//
#include <hip/hip_runtime.h>

// ---------- types & helpers ----------
typedef __attribute__((ext_vector_type(8))) short bf16x8;
typedef __attribute__((ext_vector_type(4))) float f32x4;
typedef __attribute__((ext_vector_type(4))) unsigned u32x4;

__device__ inline unsigned short f2bf(float f) {
  unsigned u = __builtin_bit_cast(unsigned, f);
  unsigned r = u + 0x7FFFu + ((u >> 16) & 1u);
  return (unsigned short)(r >> 16);
}
__device__ inline float bf2f(unsigned short s) {
  unsigned u = ((unsigned)s) << 16;
  return __builtin_bit_cast(float, u);
}
__device__ inline float fexp2(float x) { return __builtin_amdgcn_exp2f(x); }

__device__ inline void gload_lds16(const unsigned short* g, unsigned short* l) {
  __builtin_amdgcn_global_load_lds(
      (const __attribute__((address_space(1))) unsigned int*)g,
      (__attribute__((address_space(3))) unsigned int*)l, 16, 0, 0);
}

// PV key-permutation: key kappa (within 64-tile) -> slot k'
__device__ __host__ inline int pv_perm(int k) {
  return ((k >> 5) & 1) * 32 + ((k >> 2) & 3) * 8 + ((k >> 4) & 1) * 4 + (k & 3);
}

// ---------- fused preprocessing: x->bf16, 4 weight transposes, mask bias + tileok ----------
__global__ __launch_bounds__(256) void prep_kernel(
    const float* __restrict__ x, const int* __restrict__ mask,
    const float* __restrict__ w_q, const float* __restrict__ w_d,
    const float* __restrict__ w_k, const float* __restrict__ w_v,
    unsigned short* __restrict__ x_bf, unsigned short* __restrict__ wqdt,
    unsigned short* __restrict__ wkvt, float* __restrict__ bias,
    int* __restrict__ tileok) {
  int bid = blockIdx.x;
  if (bid < 1024) {  // x fp32 -> bf16
    int base = bid * 4096 + threadIdx.x * 4;
#pragma unroll
    for (int it = 0; it < 4; ++it) {
      int idx = base + it * 1024;
      float4 v = *(const float4*)&x[idx];
      ushort4 o;
      o.x = f2bf(v.x); o.y = f2bf(v.y); o.z = f2bf(v.z); o.w = f2bf(v.w);
      *(ushort4*)&x_bf[idx] = o;
    }
    return;
  }
  int tb = bid - 1024;
  if (tb >= 1408) {  // mask -> additive bias + per-64-key-tile all-valid flag
    int i = (tb - 1408) * 256 + threadIdx.x;
    int mv = mask[i];
    bias[i] = mv ? 0.0f : -1e30f;
    int ok = __all(mv != 0);
    if ((threadIdx.x & 63) == 0) tileok[i >> 6] = ok;
    return;
  }
  const float* in; unsigned short* out; int R, C, tr, tc;
  if (tb < 1024)      { in = w_q; out = wqdt;               R = 1024; C = 1024; tr = tb >> 5; tc = tb & 31; }
  else if (tb < 1152) { int t2 = tb - 1024; in = w_d; out = wqdt + 1024 * 1024; R = 1024; C = 128; tr = t2 >> 2; tc = t2 & 3; }
  else if (tb < 1280) { int t2 = tb - 1152; in = w_k; out = wkvt;               R = 128; C = 1024; tr = t2 >> 5; tc = t2 & 31; }
  else                { int t2 = tb - 1280; in = w_v; out = wkvt + 1024 * 128;  R = 128; C = 1024; tr = t2 >> 5; tc = t2 & 31; }
  __shared__ float t[32][33];
  int r0 = tr * 32, c0 = tc * 32;
  int tx = threadIdx.x & 31, ty = threadIdx.x >> 5;
  for (int r = ty; r < 32; r += 8)
    t[r][tx] = in[(size_t)(r0 + r) * C + c0 + tx];
  __syncthreads();
  for (int cc = ty; cc < 32; cc += 8)
    out[(size_t)(c0 + cc) * R + r0 + tx] = f2bf(t[tx][cc]);
}

// ---------- GEMM: C[M][N] = A[M][K] * Bt[N][K]^T ----------
template <int BN>
__global__ __launch_bounds__(256) void gemm_bt(const unsigned short* __restrict__ A, int lda,
                                               const unsigned short* __restrict__ Bt, int ldb,
                                               unsigned short* __restrict__ C, int ldc,
                                               int K) {
  constexpr int WM = (BN == 128) ? 2 : 4;
  constexpr int WN = 4 / WM;
  constexpr int MR = 128 / WM / 16;
  constexpr int NR = BN / WN / 16;
  constexpr int RPW = 128 / WM;
  constexpr int CPW = BN / WN;
  __shared__ unsigned short As[128 * 32];
  __shared__ unsigned short Bs[BN * 32];
  int m0 = blockIdx.x * 128, n0 = blockIdx.y * BN;
  int tid = threadIdx.x, w = tid >> 6, l = tid & 63;
  int lr = l & 15, lg = l >> 4;
  int wr = w / WN, wc = w % WN;
  f32x4 acc[MR][NR] = {};

  for (int k0 = 0; k0 < K; k0 += 32) {
    __syncthreads();
#pragma unroll
    for (int it = 0; it < 2; ++it) {
      int c = w * 2 + it;
      int row = c * 16 + (l >> 2);
      int col = (l & 3) * 8;
      gload_lds16(&A[(size_t)(m0 + row) * lda + k0 + col], &As[c * 512 + l * 8]);
    }
    if constexpr (BN == 128) {
#pragma unroll
      for (int it = 0; it < 2; ++it) {
        int c = w * 2 + it;
        int row = c * 16 + (l >> 2);
        int col = (l & 3) * 8;
        gload_lds16(&Bt[(size_t)(n0 + row) * ldb + k0 + col], &Bs[c * 512 + l * 8]);
      }
    } else {
      int row = w * 16 + (l >> 2);
      int col = (l & 3) * 8;
      gload_lds16(&Bt[(size_t)(n0 + row) * ldb + k0 + col], &Bs[w * 512 + l * 8]);
    }
    __syncthreads();
    bf16x8 af[MR], bfr[NR];
#pragma unroll
    for (int m = 0; m < MR; ++m)
      af[m] = *(const bf16x8*)&As[(wr * RPW + m * 16 + lr) * 32 + lg * 8];
#pragma unroll
    for (int n = 0; n < NR; ++n)
      bfr[n] = *(const bf16x8*)&Bs[(wc * CPW + n * 16 + lr) * 32 + lg * 8];
    __builtin_amdgcn_s_setprio(1);
#pragma unroll
    for (int m = 0; m < MR; ++m)
#pragma unroll
      for (int n = 0; n < NR; ++n)
        acc[m][n] = __builtin_amdgcn_mfma_f32_16x16x32_bf16(af[m], bfr[n], acc[m][n], 0, 0, 0);
    __builtin_amdgcn_s_setprio(0);
  }

#pragma unroll
  for (int m = 0; m < MR; ++m)
#pragma unroll
    for (int n = 0; n < NR; ++n)
#pragma unroll
      for (int i = 0; i < 4; ++i)
        C[(size_t)(m0 + wr * RPW + m * 16 + lg * 4 + i) * ldc + n0 + wc * CPW + n * 16 + lr] =
            f2bf(acc[m][n][i]);
}

// ---------- gemm2 with fused V transpose+permute epilogue ----------
__global__ __launch_bounds__(256) void gemm_kv(const unsigned short* __restrict__ A,
                                               const unsigned short* __restrict__ Bt,
                                               unsigned short* __restrict__ kvK,
                                               unsigned short* __restrict__ vt) {
  __shared__ unsigned short As[128 * 32];
  __shared__ unsigned short Bs[128 * 32];
  int m0 = blockIdx.x * 128, n0 = blockIdx.y * 128;
  int tid = threadIdx.x, w = tid >> 6, l = tid & 63;
  int lr = l & 15, lg = l >> 4;
  int wr = w >> 1, wc = w & 1;
  f32x4 acc[4][4] = {};

  for (int k0 = 0; k0 < 128; k0 += 32) {
    __syncthreads();
#pragma unroll
    for (int it = 0; it < 2; ++it) {
      int c = w * 2 + it;
      int row = c * 16 + (l >> 2);
      int col = (l & 3) * 8;
      gload_lds16(&A[(size_t)(m0 + row) * 1152 + k0 + col], &As[c * 512 + l * 8]);
      gload_lds16(&Bt[(size_t)(n0 + row) * 128 + k0 + col], &Bs[c * 512 + l * 8]);
    }
    __syncthreads();
    bf16x8 af[4], bfr[4];
#pragma unroll
    for (int m = 0; m < 4; ++m)
      af[m] = *(const bf16x8*)&As[(wr * 64 + m * 16 + lr) * 32 + lg * 8];
#pragma unroll
    for (int n = 0; n < 4; ++n)
      bfr[n] = *(const bf16x8*)&Bs[(wc * 64 + n * 16 + lr) * 32 + lg * 8];
    __builtin_amdgcn_s_setprio(1);
#pragma unroll
    for (int m = 0; m < 4; ++m)
#pragma unroll
      for (int n = 0; n < 4; ++n)
        acc[m][n] = __builtin_amdgcn_mfma_f32_16x16x32_bf16(af[m], bfr[n], acc[m][n], 0, 0, 0);
    __builtin_amdgcn_s_setprio(0);
  }

  if (blockIdx.y < 8) {  // K half
#pragma unroll
    for (int m = 0; m < 4; ++m)
#pragma unroll
      for (int n = 0; n < 4; ++n)
#pragma unroll
        for (int i = 0; i < 4; ++i)
          kvK[(size_t)(m0 + wr * 64 + m * 16 + lg * 4 + i) * 2048 + n0 + wc * 64 + n * 16 + lr] =
              f2bf(acc[m][n][i]);
  } else {  // V half: transposed + pv_perm'd
#pragma unroll
    for (int m = 0; m < 4; ++m)
#pragma unroll
      for (int n = 0; n < 4; ++n) {
        int vc = n0 - 1024 + wc * 64 + n * 16 + lr;
        int hh = vc >> 6, dd = vc & 63;
        int row0 = m0 + wr * 64 + m * 16 + lg * 4;
        int bb = row0 >> 11, t0 = row0 & 2047;
        size_t vrow = (size_t)((bb * 16 + hh) * 64 + dd);
        int slot = (t0 >> 6) * 64 + pv_perm(t0 & 63);
        ushort4 o;
        o.x = f2bf(acc[m][n][0]); o.y = f2bf(acc[m][n][1]);
        o.z = f2bf(acc[m][n][2]); o.w = f2bf(acc[m][n][3]);
        *(ushort4*)&vt[vrow * 2048 + slot] = o;
      }
  }
}

// ---------- flash attention: 8 warps, heavy+light band pair, dbuf LDS, 1 barrier/tile ----------
// grid (bh=32, qh=8). Block processes bands qh and 15-qh (128 q-rows each; uniform
// 34 tile-visits). Warp w owns rows band*128 + w*16 + lr. KV tiles of 64 keys,
// double-buffered in LDS, staged once per block-visit (8 warps share).
__global__ __launch_bounds__(512, 2) void attn_kernel(const unsigned short* __restrict__ qg,
                                                      const unsigned short* __restrict__ kvg,
                                                      const unsigned short* __restrict__ vtg,
                                                      const float* __restrict__ biasg,
                                                      const int* __restrict__ tileokg,
                                                      float* __restrict__ outg) {
  const int bh = blockIdx.x, qh = blockIdx.y;
  const int b = bh >> 4, h = bh & 15;
  const int tid = threadIdx.x, w = tid >> 6, l = tid & 63;
  const int lr = l & 15, lg = l >> 4;
  const int srow = tid >> 3, sc8 = (tid & 7) * 8;  // staging: 1 bf16x8/thread/tensor

  __shared__ unsigned short Ks[2][64 * 72];  // [buf][key][d]
  __shared__ unsigned short Vs[2][64 * 72];  // [buf][d][permuted key]

  const float QSCALE = 0.125f * 1.44269504089f;  // 1/sqrt(dh) * log2(e)

  for (int bi = 0; bi < 2; ++bi) {
    const int band = bi ? (15 - qh) : qh;
    const int NT = 2 * band + 2;          // KV tiles for this band
    const int qrow0 = band * 128 + w * 16;

    // Q fragments for this band
    bf16x8 qf[2];
#pragma unroll
    for (int ks = 0; ks < 2; ++ks) {
      bf16x8 raw = *(const bf16x8*)&qg[(size_t)(b * 2048 + qrow0 + lr) * 1152 + h * 64 + ks * 32 + lg * 8];
#pragma unroll
      for (int j = 0; j < 8; ++j)
        raw[j] = (short)f2bf(bf2f((unsigned short)raw[j]) * QSCALE);
      qf[ks] = raw;
    }

    f32x4 acc[4] = {};
    float m_i = -1e30f, l_part = 0.f;

    // prologue: stage tile 0 into buf 0 (guard: prior band's reads done)
    bf16x8 kreg = *(const bf16x8*)&kvg[(size_t)(b * 2048 + srow) * 2048 + h * 64 + sc8];
    bf16x8 vreg = *(const bf16x8*)&vtg[((size_t)(bh * 64 + srow)) * 2048 + sc8];
    __syncthreads();
    *(bf16x8*)&Ks[0][srow * 72 + sc8] = kreg;
    *(bf16x8*)&Vs[0][srow * 72 + sc8] = vreg;
    __syncthreads();
    int cur = 0;

    for (int kt = 0; kt < NT; ++kt) {
      // prefetch next tile into regs (hides under compute)
      if (kt + 1 < NT) {
        kreg = *(const bf16x8*)&kvg[(size_t)(b * 2048 + (kt + 1) * 64 + srow) * 2048 + h * 64 + sc8];
        vreg = *(const bf16x8*)&vtg[((size_t)(bh * 64 + srow)) * 2048 + (kt + 1) * 64 + sc8];
      }

      const int d = kt - 2 * band;  // 0 / 1 = diagonal pair tiles
      const bool skip = (d == 1) && (w < 4);
      if (!skip) {
        const bool isdiag = (d == 0 && w < 4) || (d == 1 && w >= 4);
        const int dlim = (w & 3) * 16 + lr;

        // S^T = K Q^T from Ks[cur]
        f32x4 s[4];
        __builtin_amdgcn_s_setprio(1);
#pragma unroll
        for (int n = 0; n < 4; ++n) {
          bf16x8 kf0 = *(const bf16x8*)&Ks[cur][(n * 16 + lr) * 72 + lg * 8];
          bf16x8 kf1 = *(const bf16x8*)&Ks[cur][(n * 16 + lr) * 72 + 32 + lg * 8];
          f32x4 z = {};
          z = __builtin_amdgcn_mfma_f32_16x16x32_bf16(kf0, qf[0], z, 0, 0, 0);
          z = __builtin_amdgcn_mfma_f32_16x16x32_bf16(kf1, qf[1], z, 0, 0, 0);
          s[n] = z;
        }
        __builtin_amdgcn_s_setprio(0);

        const int tok = tileokg[b * 32 + kt];
        float mx = -1e30f;
        if (tok) {
          if (isdiag) {
#pragma unroll
            for (int n = 0; n < 4; ++n)
#pragma unroll
              for (int i = 0; i < 4; ++i) {
                float v = (n * 16 + lg * 4 + i <= dlim) ? s[n][i] : -1e30f;
                s[n][i] = v;
                mx = fmaxf(mx, v);
              }
          } else {
#pragma unroll
            for (int n = 0; n < 4; ++n)
#pragma unroll
              for (int i = 0; i < 4; ++i)
                mx = fmaxf(mx, s[n][i]);
          }
        } else {  // rare general-mask path
#pragma unroll
          for (int n = 0; n < 4; ++n)
#pragma unroll
            for (int i = 0; i < 4; ++i) {
              int keyl = n * 16 + lg * 4 + i;
              float v = s[n][i] + biasg[b * 2048 + kt * 64 + keyl];
              if (isdiag) v = (keyl <= dlim) ? v : -1e30f;
              s[n][i] = v;
              mx = fmaxf(mx, v);
            }
        }
        mx = fmaxf(mx, __shfl_xor(mx, 16, 64));
        mx = fmaxf(mx, __shfl_xor(mx, 32, 64));

        // T13 defer-rescale (THR=8 in log2 domain)
        if (__any(mx - m_i > 8.0f)) {
          float mn = fmaxf(m_i, mx);
          float sc = fexp2(m_i - mn);
          m_i = mn;
          l_part *= sc;
          float scb[4];
#pragma unroll
          for (int i = 0; i < 4; ++i) scb[i] = __shfl(sc, lg * 4 + i, 64);
#pragma unroll
          for (int dt = 0; dt < 4; ++dt)
#pragma unroll
            for (int i = 0; i < 4; ++i) acc[dt][i] *= scb[i];
        }

        float rs = 0.f;
#pragma unroll
        for (int n = 0; n < 4; ++n)
#pragma unroll
          for (int i = 0; i < 4; ++i) {
            float e = fexp2(s[n][i] - m_i);
            s[n][i] = e;
            rs += e;
          }
        l_part += rs;

        // P -> PV A-fragments in registers (V pre-permuted by pv_perm)
        unsigned pk[4][2];
#pragma unroll
        for (int n = 0; n < 4; ++n) {
          asm("v_cvt_pk_bf16_f32 %0, %1, %2" : "=v"(pk[n][0]) : "v"(s[n][0]), "v"(s[n][1]));
          asm("v_cvt_pk_bf16_f32 %0, %1, %2" : "=v"(pk[n][1]) : "v"(s[n][2]), "v"(s[n][3]));
        }
        bf16x8 paf[2];
#pragma unroll
        for (int ks = 0; ks < 2; ++ks) {
          u32x4 uv;
          uv[0] = pk[2 * ks][0];
          uv[1] = pk[2 * ks][1];
          uv[2] = pk[2 * ks + 1][0];
          uv[3] = pk[2 * ks + 1][1];
          paf[ks] = __builtin_bit_cast(bf16x8, uv);
        }

        // O += P V from Vs[cur]
        __builtin_amdgcn_s_setprio(1);
#pragma unroll
        for (int ks = 0; ks < 2; ++ks)
#pragma unroll
          for (int dt = 0; dt < 4; ++dt) {
            bf16x8 vf = *(const bf16x8*)&Vs[cur][(dt * 16 + lr) * 72 + ks * 32 + lg * 8];
            acc[dt] = __builtin_amdgcn_mfma_f32_16x16x32_bf16(paf[ks], vf, acc[dt], 0, 0, 0);
          }
        __builtin_amdgcn_s_setprio(0);
      }

      // write next tile into the other buffer; single barrier per tile
      if (kt + 1 < NT) {
        *(bf16x8*)&Ks[cur ^ 1][srow * 72 + sc8] = kreg;
        *(bf16x8*)&Vs[cur ^ 1][srow * 72 + sc8] = vreg;
        __syncthreads();
        cur ^= 1;
      }
    }

    // epilogue: finish l reduction, normalize, store this band
    float lt = l_part;
    lt += __shfl_xor(lt, 16, 64);
    lt += __shfl_xor(lt, 32, 64);
    float inv = 1.f / lt;
    float invb[4];
#pragma unroll
    for (int i = 0; i < 4; ++i) invb[i] = __shfl(inv, lg * 4 + i, 64);
#pragma unroll
    for (int dt = 0; dt < 4; ++dt)
#pragma unroll
      for (int i = 0; i < 4; ++i)
        outg[(size_t)(b * 2048 + qrow0 + lg * 4 + i) * 1024 + h * 64 + dt * 16 + lr] =
            acc[dt][i] * invb[i];
  }
}

// ---------- launch ----------
extern "C" void kernel_launch(void* const* d_in, const int* in_sizes, int n_in,
                              void* d_out, int out_size, void* d_ws, size_t ws_size,
                              hipStream_t stream) {
  const float* x    = (const float*)d_in[0];
  const int*   mask = (const int*)d_in[1];
  const float* w_q  = (const float*)d_in[2];
  const float* w_d  = (const float*)d_in[3];
  const float* w_k  = (const float*)d_in[4];
  const float* w_v  = (const float*)d_in[5];
  float* out = (float*)d_out;

  char* ws = (char*)d_ws;
  size_t off = 0;
  auto alloc = [&](size_t elems) {
    unsigned short* p = (unsigned short*)(ws + off);
    off += ((elems * 2 + 255) & ~(size_t)255);
    return p;
  };
  unsigned short* x_bf = alloc(4194304);      // [4096][1024]
  unsigned short* wqdt = alloc(1152 * 1024);  // [1152][1024]
  unsigned short* wkvt = alloc(2048 * 128);   // [2048][128]
  unsigned short* qlat = alloc(4096 * 1152);  // [4096][1152]: q | latent
  unsigned short* kv   = alloc(4096 * 2048);  // [4096][2048]: K in cols 0..1023
  unsigned short* vt   = alloc(4194304);      // [32][64][2048], pv_perm'd
  float* bias = (float*)alloc(8192);          // 4096 floats
  int* tileok = (int*)alloc(128);             // 64 ints

  prep_kernel<<<2448, 256, 0, stream>>>(x, mask, w_q, w_d, w_k, w_v, x_bf, wqdt, wkvt, bias, tileok);

  gemm_bt<64><<<dim3(32, 18), 256, 0, stream>>>(x_bf, 1024, wqdt, 1024, qlat, 1152, 1024);
  gemm_kv<<<dim3(32, 16), 256, 0, stream>>>(qlat + 1024, wkvt, kv, vt);

  attn_kernel<<<dim3(32, 8), 512, 0, stream>>>(qlat, kv, vt, bias, tileok, out);
}

// Round 16
// 74.750 us; speedup vs baseline: 1.2408x; 1.1268x over previous
//
#include <hip/hip_runtime.h>

// ---------- types & helpers ----------
typedef __attribute__((ext_vector_type(8))) short bf16x8;
typedef __attribute__((ext_vector_type(4))) float f32x4;
typedef __attribute__((ext_vector_type(4))) unsigned u32x4;

__device__ inline unsigned short f2bf(float f) {
  unsigned u = __builtin_bit_cast(unsigned, f);
  unsigned r = u + 0x7FFFu + ((u >> 16) & 1u);
  return (unsigned short)(r >> 16);
}
__device__ inline float bf2f(unsigned short s) {
  unsigned u = ((unsigned)s) << 16;
  return __builtin_bit_cast(float, u);
}
__device__ inline float fexp2(float x) { return __builtin_amdgcn_exp2f(x); }

__device__ inline void gload_lds16(const unsigned short* g, unsigned short* l) {
  __builtin_amdgcn_global_load_lds(
      (const __attribute__((address_space(1))) unsigned int*)g,
      (__attribute__((address_space(3))) unsigned int*)l, 16, 0, 0);
}

// PV key-permutation: key kappa (within 64-tile) -> slot k'
__device__ __host__ inline int pv_perm(int k) {
  return ((k >> 5) & 1) * 32 + ((k >> 2) & 3) * 8 + ((k >> 4) & 1) * 4 + (k & 3);
}

// ---------- fused preprocessing: x->bf16, 4 weight transposes, mask bias + tileok ----------
__global__ __launch_bounds__(256) void prep_kernel(
    const float* __restrict__ x, const int* __restrict__ mask,
    const float* __restrict__ w_q, const float* __restrict__ w_d,
    const float* __restrict__ w_k, const float* __restrict__ w_v,
    unsigned short* __restrict__ x_bf, unsigned short* __restrict__ wqdt,
    unsigned short* __restrict__ wkvt, float* __restrict__ bias,
    int* __restrict__ tileok) {
  int bid = blockIdx.x;
  if (bid < 1024) {  // x fp32 -> bf16
    int base = bid * 4096 + threadIdx.x * 4;
#pragma unroll
    for (int it = 0; it < 4; ++it) {
      int idx = base + it * 1024;
      float4 v = *(const float4*)&x[idx];
      ushort4 o;
      o.x = f2bf(v.x); o.y = f2bf(v.y); o.z = f2bf(v.z); o.w = f2bf(v.w);
      *(ushort4*)&x_bf[idx] = o;
    }
    return;
  }
  int tb = bid - 1024;
  if (tb >= 1408) {  // mask -> additive bias + per-64-key-tile all-valid flag
    int i = (tb - 1408) * 256 + threadIdx.x;
    int mv = mask[i];
    bias[i] = mv ? 0.0f : -1e30f;
    int ok = __all(mv != 0);
    if ((threadIdx.x & 63) == 0) tileok[i >> 6] = ok;
    return;
  }
  const float* in; unsigned short* out; int R, C, tr, tc;
  if (tb < 1024)      { in = w_q; out = wqdt;               R = 1024; C = 1024; tr = tb >> 5; tc = tb & 31; }
  else if (tb < 1152) { int t2 = tb - 1024; in = w_d; out = wqdt + 1024 * 1024; R = 1024; C = 128; tr = t2 >> 2; tc = t2 & 3; }
  else if (tb < 1280) { int t2 = tb - 1152; in = w_k; out = wkvt;               R = 128; C = 1024; tr = t2 >> 5; tc = t2 & 31; }
  else                { int t2 = tb - 1280; in = w_v; out = wkvt + 1024 * 128;  R = 128; C = 1024; tr = t2 >> 5; tc = t2 & 31; }
  __shared__ float t[32][33];
  int r0 = tr * 32, c0 = tc * 32;
  int tx = threadIdx.x & 31, ty = threadIdx.x >> 5;
  for (int r = ty; r < 32; r += 8)
    t[r][tx] = in[(size_t)(r0 + r) * C + c0 + tx];
  __syncthreads();
  for (int cc = ty; cc < 32; cc += 8)
    out[(size_t)(c0 + cc) * R + r0 + tx] = f2bf(t[tx][cc]);
}

// ---------- gemm1: qlat[4096][1152] = x_bf[4096][1024] * wqdt[1152][1024]^T ----------
// Tile 128x64, BK=64 via dual BK=32 panels (conflict-free layout, 1 barrier pair / 64 K)
__global__ __launch_bounds__(256) void gemm_q(const unsigned short* __restrict__ A,
                                              const unsigned short* __restrict__ Bt,
                                              unsigned short* __restrict__ C) {
  __shared__ unsigned short As[2][128 * 32];
  __shared__ unsigned short Bs[2][64 * 32];
  int m0 = blockIdx.x * 128, n0 = blockIdx.y * 64;
  int tid = threadIdx.x, w = tid >> 6, l = tid & 63;
  int lr = l & 15, lg = l >> 4;
  f32x4 acc[2][4] = {};

  for (int k0 = 0; k0 < 1024; k0 += 64) {
    __syncthreads();
#pragma unroll
    for (int it = 0; it < 4; ++it) {
      int s = w * 4 + it;            // 16 A slots: panel p, chunk c (16 rows)
      int p = s >> 3, c = s & 7;
      int row = c * 16 + (l >> 2), col = (l & 3) * 8;
      gload_lds16(&A[(size_t)(m0 + row) * 1024 + k0 + p * 32 + col], &As[p][c * 512 + l * 8]);
    }
#pragma unroll
    for (int it = 0; it < 2; ++it) {
      int s = w * 2 + it;            // 8 B slots
      int p = s >> 2, c = s & 3;
      int row = c * 16 + (l >> 2), col = (l & 3) * 8;
      gload_lds16(&Bt[(size_t)(n0 + row) * 1024 + k0 + p * 32 + col], &Bs[p][c * 512 + l * 8]);
    }
    __syncthreads();
#pragma unroll
    for (int p = 0; p < 2; ++p) {
      bf16x8 af[2], bfr[4];
#pragma unroll
      for (int m = 0; m < 2; ++m)
        af[m] = *(const bf16x8*)&As[p][(w * 32 + m * 16 + lr) * 32 + lg * 8];
#pragma unroll
      for (int n = 0; n < 4; ++n)
        bfr[n] = *(const bf16x8*)&Bs[p][(n * 16 + lr) * 32 + lg * 8];
      __builtin_amdgcn_s_setprio(1);
#pragma unroll
      for (int m = 0; m < 2; ++m)
#pragma unroll
        for (int n = 0; n < 4; ++n)
          acc[m][n] = __builtin_amdgcn_mfma_f32_16x16x32_bf16(af[m], bfr[n], acc[m][n], 0, 0, 0);
      __builtin_amdgcn_s_setprio(0);
    }
  }

#pragma unroll
  for (int m = 0; m < 2; ++m)
#pragma unroll
    for (int n = 0; n < 4; ++n)
#pragma unroll
      for (int i = 0; i < 4; ++i)
        C[(size_t)(m0 + w * 32 + m * 16 + lg * 4 + i) * 1152 + n0 + n * 16 + lr] =
            f2bf(acc[m][n][i]);
}

// ---------- gemm2 with fused V transpose+permute epilogue ----------
__global__ __launch_bounds__(256) void gemm_kv(const unsigned short* __restrict__ A,
                                               const unsigned short* __restrict__ Bt,
                                               unsigned short* __restrict__ kvK,
                                               unsigned short* __restrict__ vt) {
  __shared__ unsigned short As[128 * 32];
  __shared__ unsigned short Bs[128 * 32];
  int m0 = blockIdx.x * 128, n0 = blockIdx.y * 128;
  int tid = threadIdx.x, w = tid >> 6, l = tid & 63;
  int lr = l & 15, lg = l >> 4;
  int wr = w >> 1, wc = w & 1;
  f32x4 acc[4][4] = {};

  for (int k0 = 0; k0 < 128; k0 += 32) {
    __syncthreads();
#pragma unroll
    for (int it = 0; it < 2; ++it) {
      int c = w * 2 + it;
      int row = c * 16 + (l >> 2);
      int col = (l & 3) * 8;
      gload_lds16(&A[(size_t)(m0 + row) * 1152 + k0 + col], &As[c * 512 + l * 8]);
      gload_lds16(&Bt[(size_t)(n0 + row) * 128 + k0 + col], &Bs[c * 512 + l * 8]);
    }
    __syncthreads();
    bf16x8 af[4], bfr[4];
#pragma unroll
    for (int m = 0; m < 4; ++m)
      af[m] = *(const bf16x8*)&As[(wr * 64 + m * 16 + lr) * 32 + lg * 8];
#pragma unroll
    for (int n = 0; n < 4; ++n)
      bfr[n] = *(const bf16x8*)&Bs[(wc * 64 + n * 16 + lr) * 32 + lg * 8];
    __builtin_amdgcn_s_setprio(1);
#pragma unroll
    for (int m = 0; m < 4; ++m)
#pragma unroll
      for (int n = 0; n < 4; ++n)
        acc[m][n] = __builtin_amdgcn_mfma_f32_16x16x32_bf16(af[m], bfr[n], acc[m][n], 0, 0, 0);
    __builtin_amdgcn_s_setprio(0);
  }

  if (blockIdx.y < 8) {  // K half
#pragma unroll
    for (int m = 0; m < 4; ++m)
#pragma unroll
      for (int n = 0; n < 4; ++n)
#pragma unroll
        for (int i = 0; i < 4; ++i)
          kvK[(size_t)(m0 + wr * 64 + m * 16 + lg * 4 + i) * 2048 + n0 + wc * 64 + n * 16 + lr] =
              f2bf(acc[m][n][i]);
  } else {  // V half: transposed + pv_perm'd
#pragma unroll
    for (int m = 0; m < 4; ++m)
#pragma unroll
      for (int n = 0; n < 4; ++n) {
        int vc = n0 - 1024 + wc * 64 + n * 16 + lr;
        int hh = vc >> 6, dd = vc & 63;
        int row0 = m0 + wr * 64 + m * 16 + lg * 4;
        int bb = row0 >> 11, t0 = row0 & 2047;
        size_t vrow = (size_t)((bb * 16 + hh) * 64 + dd);
        int slot = (t0 >> 6) * 64 + pv_perm(t0 & 63);
        ushort4 o;
        o.x = f2bf(acc[m][n][0]); o.y = f2bf(acc[m][n][1]);
        o.z = f2bf(acc[m][n][2]); o.w = f2bf(acc[m][n][3]);
        *(ushort4*)&vt[vrow * 2048 + slot] = o;
      }
  }
}

// ---------- flash attention: 4 warps, paired 64-row bands, dbuf LDS, 1 barrier/tile ----------
// grid (bh=32, pr=16). Block processes bands pr and 31-pr (uniform 33 tile-visits).
// 512 blocks = 2 independent barrier-groups per CU. Warp w owns rows band*64+w*16..+15.
__global__ __launch_bounds__(256, 2) void attn_kernel(const unsigned short* __restrict__ qg,
                                                      const unsigned short* __restrict__ kvg,
                                                      const unsigned short* __restrict__ vtg,
                                                      const float* __restrict__ biasg,
                                                      const int* __restrict__ tileokg,
                                                      float* __restrict__ outg) {
  const int bh = blockIdx.x, pr = blockIdx.y;
  const int b = bh >> 4, h = bh & 15;
  const int tid = threadIdx.x, w = tid >> 6, l = tid & 63;
  const int lr = l & 15, lg = l >> 4;

  __shared__ unsigned short Ks[2][64 * 72];  // [buf][key][d]
  __shared__ unsigned short Vs[2][64 * 72];  // [buf][d][permuted key]

  const float QSCALE = 0.125f * 1.44269504089f;  // 1/sqrt(dh) * log2(e)

  for (int bi = 0; bi < 2; ++bi) {
    const int band = bi ? (31 - pr) : pr;  // 64-row band
    const int NT = band + 1;               // KV tiles for this band
    const int qrow0 = band * 64 + w * 16;

    // Q fragments for this band
    bf16x8 qf[2];
#pragma unroll
    for (int ks = 0; ks < 2; ++ks) {
      bf16x8 raw = *(const bf16x8*)&qg[(size_t)(b * 2048 + qrow0 + lr) * 1152 + h * 64 + ks * 32 + lg * 8];
#pragma unroll
      for (int j = 0; j < 8; ++j)
        raw[j] = (short)f2bf(bf2f((unsigned short)raw[j]) * QSCALE);
      qf[ks] = raw;
    }

    f32x4 acc[4] = {};
    float m_i = -1e30f, l_part = 0.f;

    // prologue: stage tile 0 into buf 0 (guard: prior band's reads done)
    bf16x8 kreg[2], vreg[2];
#pragma unroll
    for (int it = 0; it < 2; ++it) {
      int slot = it * 256 + tid, row = slot >> 3, c8 = (slot & 7) * 8;
      kreg[it] = *(const bf16x8*)&kvg[(size_t)(b * 2048 + row) * 2048 + h * 64 + c8];
      vreg[it] = *(const bf16x8*)&vtg[((size_t)(bh * 64 + row)) * 2048 + c8];
    }
    __syncthreads();
#pragma unroll
    for (int it = 0; it < 2; ++it) {
      int slot = it * 256 + tid, row = slot >> 3, c8 = (slot & 7) * 8;
      *(bf16x8*)&Ks[0][row * 72 + c8] = kreg[it];
      *(bf16x8*)&Vs[0][row * 72 + c8] = vreg[it];
    }
    __syncthreads();
    int cur = 0;

    for (int kt = 0; kt < NT; ++kt) {
      // prefetch next tile into regs (hides under compute)
      if (kt + 1 < NT) {
#pragma unroll
        for (int it = 0; it < 2; ++it) {
          int slot = it * 256 + tid, row = slot >> 3, c8 = (slot & 7) * 8;
          kreg[it] = *(const bf16x8*)&kvg[(size_t)(b * 2048 + (kt + 1) * 64 + row) * 2048 + h * 64 + c8];
          vreg[it] = *(const bf16x8*)&vtg[((size_t)(bh * 64 + row)) * 2048 + (kt + 1) * 64 + c8];
        }
      }

      const bool diag = (kt == NT - 1);
      const int dlim = w * 16 + lr;  // causal limit within diag tile

      // S^T = K Q^T from Ks[cur]
      f32x4 s[4];
      __builtin_amdgcn_s_setprio(1);
#pragma unroll
      for (int n = 0; n < 4; ++n) {
        bf16x8 kf0 = *(const bf16x8*)&Ks[cur][(n * 16 + lr) * 72 + lg * 8];
        bf16x8 kf1 = *(const bf16x8*)&Ks[cur][(n * 16 + lr) * 72 + 32 + lg * 8];
        f32x4 z = {};
        z = __builtin_amdgcn_mfma_f32_16x16x32_bf16(kf0, qf[0], z, 0, 0, 0);
        z = __builtin_amdgcn_mfma_f32_16x16x32_bf16(kf1, qf[1], z, 0, 0, 0);
        s[n] = z;
      }
      __builtin_amdgcn_s_setprio(0);

      const int tok = tileokg[b * 32 + kt];
      float mx = -1e30f;
      if (tok) {
        if (diag) {
#pragma unroll
          for (int n = 0; n < 4; ++n)
#pragma unroll
            for (int i = 0; i < 4; ++i) {
              float v = (n * 16 + lg * 4 + i <= dlim) ? s[n][i] : -1e30f;
              s[n][i] = v;
              mx = fmaxf(mx, v);
            }
        } else {
#pragma unroll
          for (int n = 0; n < 4; ++n)
#pragma unroll
            for (int i = 0; i < 4; ++i)
              mx = fmaxf(mx, s[n][i]);
        }
      } else {  // rare general-mask path
#pragma unroll
        for (int n = 0; n < 4; ++n)
#pragma unroll
          for (int i = 0; i < 4; ++i) {
            int keyl = n * 16 + lg * 4 + i;
            float v = s[n][i] + biasg[b * 2048 + kt * 64 + keyl];
            if (diag) v = (keyl <= dlim) ? v : -1e30f;
            s[n][i] = v;
            mx = fmaxf(mx, v);
          }
      }
      mx = fmaxf(mx, __shfl_xor(mx, 16, 64));
      mx = fmaxf(mx, __shfl_xor(mx, 32, 64));

      // T13 defer-rescale (THR=8 in log2 domain)
      if (__any(mx - m_i > 8.0f)) {
        float mn = fmaxf(m_i, mx);
        float sc = fexp2(m_i - mn);
        m_i = mn;
        l_part *= sc;
        float scb[4];
#pragma unroll
        for (int i = 0; i < 4; ++i) scb[i] = __shfl(sc, lg * 4 + i, 64);
#pragma unroll
        for (int dt = 0; dt < 4; ++dt)
#pragma unroll
          for (int i = 0; i < 4; ++i) acc[dt][i] *= scb[i];
      }

      float rs = 0.f;
#pragma unroll
      for (int n = 0; n < 4; ++n)
#pragma unroll
        for (int i = 0; i < 4; ++i) {
          float e = fexp2(s[n][i] - m_i);
          s[n][i] = e;
          rs += e;
        }
      l_part += rs;

      // P -> PV A-fragments in registers (V pre-permuted by pv_perm)
      unsigned pk[4][2];
#pragma unroll
      for (int n = 0; n < 4; ++n) {
        asm("v_cvt_pk_bf16_f32 %0, %1, %2" : "=v"(pk[n][0]) : "v"(s[n][0]), "v"(s[n][1]));
        asm("v_cvt_pk_bf16_f32 %0, %1, %2" : "=v"(pk[n][1]) : "v"(s[n][2]), "v"(s[n][3]));
      }
      bf16x8 paf[2];
#pragma unroll
      for (int ks = 0; ks < 2; ++ks) {
        u32x4 uv;
        uv[0] = pk[2 * ks][0];
        uv[1] = pk[2 * ks][1];
        uv[2] = pk[2 * ks + 1][0];
        uv[3] = pk[2 * ks + 1][1];
        paf[ks] = __builtin_bit_cast(bf16x8, uv);
      }

      // O += P V from Vs[cur]
      __builtin_amdgcn_s_setprio(1);
#pragma unroll
      for (int ks = 0; ks < 2; ++ks)
#pragma unroll
        for (int dt = 0; dt < 4; ++dt) {
          bf16x8 vf = *(const bf16x8*)&Vs[cur][(dt * 16 + lr) * 72 + ks * 32 + lg * 8];
          acc[dt] = __builtin_amdgcn_mfma_f32_16x16x32_bf16(paf[ks], vf, acc[dt], 0, 0, 0);
        }
      __builtin_amdgcn_s_setprio(0);

      // write next tile into the other buffer; single barrier per tile
      if (kt + 1 < NT) {
#pragma unroll
        for (int it = 0; it < 2; ++it) {
          int slot = it * 256 + tid, row = slot >> 3, c8 = (slot & 7) * 8;
          *(bf16x8*)&Ks[cur ^ 1][row * 72 + c8] = kreg[it];
          *(bf16x8*)&Vs[cur ^ 1][row * 72 + c8] = vreg[it];
        }
        __syncthreads();
        cur ^= 1;
      }
    }

    // epilogue: finish l reduction, normalize, store this band
    float lt = l_part;
    lt += __shfl_xor(lt, 16, 64);
    lt += __shfl_xor(lt, 32, 64);
    float inv = 1.f / lt;
    float invb[4];
#pragma unroll
    for (int i = 0; i < 4; ++i) invb[i] = __shfl(inv, lg * 4 + i, 64);
#pragma unroll
    for (int dt = 0; dt < 4; ++dt)
#pragma unroll
      for (int i = 0; i < 4; ++i)
        outg[(size_t)(b * 2048 + qrow0 + lg * 4 + i) * 1024 + h * 64 + dt * 16 + lr] =
            acc[dt][i] * invb[i];
  }
}

// ---------- launch ----------
extern "C" void kernel_launch(void* const* d_in, const int* in_sizes, int n_in,
                              void* d_out, int out_size, void* d_ws, size_t ws_size,
                              hipStream_t stream) {
  const float* x    = (const float*)d_in[0];
  const int*   mask = (const int*)d_in[1];
  const float* w_q  = (const float*)d_in[2];
  const float* w_d  = (const float*)d_in[3];
  const float* w_k  = (const float*)d_in[4];
  const float* w_v  = (const float*)d_in[5];
  float* out = (float*)d_out;

  char* ws = (char*)d_ws;
  size_t off = 0;
  auto alloc = [&](size_t elems) {
    unsigned short* p = (unsigned short*)(ws + off);
    off += ((elems * 2 + 255) & ~(size_t)255);
    return p;
  };
  unsigned short* x_bf = alloc(4194304);      // [4096][1024]
  unsigned short* wqdt = alloc(1152 * 1024);  // [1152][1024]
  unsigned short* wkvt = alloc(2048 * 128);   // [2048][128]
  unsigned short* qlat = alloc(4096 * 1152);  // [4096][1152]: q | latent
  unsigned short* kv   = alloc(4096 * 2048);  // [4096][2048]: K in cols 0..1023
  unsigned short* vt   = alloc(4194304);      // [32][64][2048], pv_perm'd
  float* bias = (float*)alloc(8192);          // 4096 floats
  int* tileok = (int*)alloc(128);             // 64 ints

  prep_kernel<<<2448, 256, 0, stream>>>(x, mask, w_q, w_d, w_k, w_v, x_bf, wqdt, wkvt, bias, tileok);

  gemm_q<<<dim3(32, 18), 256, 0, stream>>>(x_bf, wqdt, qlat);
  gemm_kv<<<dim3(32, 16), 256, 0, stream>>>(qlat + 1024, wkvt, kv, vt);

  attn_kernel<<<dim3(32, 16), 256, 0, stream>>>(qlat, kv, vt, bias, tileok, out);
}

// Round 20
// 72.887 us; speedup vs baseline: 1.2725x; 1.0256x over previous
//
#include <hip/hip_runtime.h>

// ---------- types & helpers ----------
typedef __attribute__((ext_vector_type(8))) short bf16x8;
typedef __attribute__((ext_vector_type(4))) float f32x4;
typedef __attribute__((ext_vector_type(4))) unsigned u32x4;

__device__ inline unsigned short f2bf(float f) {
  unsigned u = __builtin_bit_cast(unsigned, f);
  unsigned r = u + 0x7FFFu + ((u >> 16) & 1u);
  return (unsigned short)(r >> 16);
}
__device__ inline float bf2f(unsigned short s) {
  unsigned u = ((unsigned)s) << 16;
  return __builtin_bit_cast(float, u);
}
__device__ inline float fexp2(float x) { return __builtin_amdgcn_exp2f(x); }

__device__ inline void gload_lds16(const unsigned short* g, unsigned short* l) {
  __builtin_amdgcn_global_load_lds(
      (const __attribute__((address_space(1))) unsigned int*)g,
      (__attribute__((address_space(3))) unsigned int*)l, 16, 0, 0);
}

// PV key-permutation: key kappa (within 64-tile) -> slot k'
__device__ __host__ inline int pv_perm(int k) {
  return ((k >> 5) & 1) * 32 + ((k >> 2) & 3) * 8 + ((k >> 4) & 1) * 4 + (k & 3);
}

// ---------- fused preprocessing: x->bf16, 4 weight transposes, mask bias + tileok ----------
__global__ __launch_bounds__(256) void prep_kernel(
    const float* __restrict__ x, const int* __restrict__ mask,
    const float* __restrict__ w_q, const float* __restrict__ w_d,
    const float* __restrict__ w_k, const float* __restrict__ w_v,
    unsigned short* __restrict__ x_bf, unsigned short* __restrict__ wqdt,
    unsigned short* __restrict__ wkvt, float* __restrict__ bias,
    int* __restrict__ tileok) {
  int bid = blockIdx.x;
  if (bid < 1024) {  // x fp32 -> bf16
    int base = bid * 4096 + threadIdx.x * 4;
#pragma unroll
    for (int it = 0; it < 4; ++it) {
      int idx = base + it * 1024;
      float4 v = *(const float4*)&x[idx];
      ushort4 o;
      o.x = f2bf(v.x); o.y = f2bf(v.y); o.z = f2bf(v.z); o.w = f2bf(v.w);
      *(ushort4*)&x_bf[idx] = o;
    }
    return;
  }
  int tb = bid - 1024;
  if (tb >= 1408) {  // mask -> additive bias + per-64-key-tile all-valid flag
    int i = (tb - 1408) * 256 + threadIdx.x;
    int mv = mask[i];
    bias[i] = mv ? 0.0f : -1e30f;
    int ok = __all(mv != 0);
    if ((threadIdx.x & 63) == 0) tileok[i >> 6] = ok;
    return;
  }
  const float* in; unsigned short* out; int R, C, tr, tc;
  if (tb < 1024)      { in = w_q; out = wqdt;               R = 1024; C = 1024; tr = tb >> 5; tc = tb & 31; }
  else if (tb < 1152) { int t2 = tb - 1024; in = w_d; out = wqdt + 1024 * 1024; R = 1024; C = 128; tr = t2 >> 2; tc = t2 & 3; }
  else if (tb < 1280) { int t2 = tb - 1152; in = w_k; out = wkvt;               R = 128; C = 1024; tr = t2 >> 5; tc = t2 & 31; }
  else                { int t2 = tb - 1280; in = w_v; out = wkvt + 1024 * 128;  R = 128; C = 1024; tr = t2 >> 5; tc = t2 & 31; }
  __shared__ float t[32][33];
  int r0 = tr * 32, c0 = tc * 32;
  int tx = threadIdx.x & 31, ty = threadIdx.x >> 5;
  for (int r = ty; r < 32; r += 8)
    t[r][tx] = in[(size_t)(r0 + r) * C + c0 + tx];
  __syncthreads();
  for (int cc = ty; cc < 32; cc += 8)
    out[(size_t)(c0 + cc) * R + r0 + tx] = f2bf(t[tx][cc]);
}

// ---------- gemm1: qlat[4096][1152] = x_bf[4096][1024] * wqdt[1152][1024]^T ----------
// Tile 128x64, BK=64 via dual BK=32 panels (conflict-free layout, 1 barrier pair / 64 K)
__global__ __launch_bounds__(256) void gemm_q(const unsigned short* __restrict__ A,
                                              const unsigned short* __restrict__ Bt,
                                              unsigned short* __restrict__ C) {
  __shared__ unsigned short As[2][128 * 32];
  __shared__ unsigned short Bs[2][64 * 32];
  int m0 = blockIdx.x * 128, n0 = blockIdx.y * 64;
  int tid = threadIdx.x, w = tid >> 6, l = tid & 63;
  int lr = l & 15, lg = l >> 4;
  f32x4 acc[2][4] = {};

  for (int k0 = 0; k0 < 1024; k0 += 64) {
    __syncthreads();
#pragma unroll
    for (int it = 0; it < 4; ++it) {
      int s = w * 4 + it;            // 16 A slots: panel p, chunk c (16 rows)
      int p = s >> 3, c = s & 7;
      int row = c * 16 + (l >> 2), col = (l & 3) * 8;
      gload_lds16(&A[(size_t)(m0 + row) * 1024 + k0 + p * 32 + col], &As[p][c * 512 + l * 8]);
    }
#pragma unroll
    for (int it = 0; it < 2; ++it) {
      int s = w * 2 + it;            // 8 B slots
      int p = s >> 2, c = s & 3;
      int row = c * 16 + (l >> 2), col = (l & 3) * 8;
      gload_lds16(&Bt[(size_t)(n0 + row) * 1024 + k0 + p * 32 + col], &Bs[p][c * 512 + l * 8]);
    }
    __syncthreads();
#pragma unroll
    for (int p = 0; p < 2; ++p) {
      bf16x8 af[2], bfr[4];
#pragma unroll
      for (int m = 0; m < 2; ++m)
        af[m] = *(const bf16x8*)&As[p][(w * 32 + m * 16 + lr) * 32 + lg * 8];
#pragma unroll
      for (int n = 0; n < 4; ++n)
        bfr[n] = *(const bf16x8*)&Bs[p][(n * 16 + lr) * 32 + lg * 8];
      __builtin_amdgcn_s_setprio(1);
#pragma unroll
      for (int m = 0; m < 2; ++m)
#pragma unroll
        for (int n = 0; n < 4; ++n)
          acc[m][n] = __builtin_amdgcn_mfma_f32_16x16x32_bf16(af[m], bfr[n], acc[m][n], 0, 0, 0);
      __builtin_amdgcn_s_setprio(0);
    }
  }

#pragma unroll
  for (int m = 0; m < 2; ++m)
#pragma unroll
    for (int n = 0; n < 4; ++n)
#pragma unroll
      for (int i = 0; i < 4; ++i)
        C[(size_t)(m0 + w * 32 + m * 16 + lg * 4 + i) * 1152 + n0 + n * 16 + lr] =
            f2bf(acc[m][n][i]);
}

// ---------- gemm2 with fused V transpose+permute epilogue ----------
__global__ __launch_bounds__(256) void gemm_kv(const unsigned short* __restrict__ A,
                                               const unsigned short* __restrict__ Bt,
                                               unsigned short* __restrict__ kvK,
                                               unsigned short* __restrict__ vt) {
  __shared__ unsigned short As[128 * 32];
  __shared__ unsigned short Bs[128 * 32];
  int m0 = blockIdx.x * 128, n0 = blockIdx.y * 128;
  int tid = threadIdx.x, w = tid >> 6, l = tid & 63;
  int lr = l & 15, lg = l >> 4;
  int wr = w >> 1, wc = w & 1;
  f32x4 acc[4][4] = {};

  for (int k0 = 0; k0 < 128; k0 += 32) {
    __syncthreads();
#pragma unroll
    for (int it = 0; it < 2; ++it) {
      int c = w * 2 + it;
      int row = c * 16 + (l >> 2);
      int col = (l & 3) * 8;
      gload_lds16(&A[(size_t)(m0 + row) * 1152 + k0 + col], &As[c * 512 + l * 8]);
      gload_lds16(&Bt[(size_t)(n0 + row) * 128 + k0 + col], &Bs[c * 512 + l * 8]);
    }
    __syncthreads();
    bf16x8 af[4], bfr[4];
#pragma unroll
    for (int m = 0; m < 4; ++m)
      af[m] = *(const bf16x8*)&As[(wr * 64 + m * 16 + lr) * 32 + lg * 8];
#pragma unroll
    for (int n = 0; n < 4; ++n)
      bfr[n] = *(const bf16x8*)&Bs[(wc * 64 + n * 16 + lr) * 32 + lg * 8];
    __builtin_amdgcn_s_setprio(1);
#pragma unroll
    for (int m = 0; m < 4; ++m)
#pragma unroll
      for (int n = 0; n < 4; ++n)
        acc[m][n] = __builtin_amdgcn_mfma_f32_16x16x32_bf16(af[m], bfr[n], acc[m][n], 0, 0, 0);
    __builtin_amdgcn_s_setprio(0);
  }

  if (blockIdx.y < 8) {  // K half
#pragma unroll
    for (int m = 0; m < 4; ++m)
#pragma unroll
      for (int n = 0; n < 4; ++n)
#pragma unroll
        for (int i = 0; i < 4; ++i)
          kvK[(size_t)(m0 + wr * 64 + m * 16 + lg * 4 + i) * 2048 + n0 + wc * 64 + n * 16 + lr] =
              f2bf(acc[m][n][i]);
  } else {  // V half: transposed + pv_perm'd
#pragma unroll
    for (int m = 0; m < 4; ++m)
#pragma unroll
      for (int n = 0; n < 4; ++n) {
        int vc = n0 - 1024 + wc * 64 + n * 16 + lr;
        int hh = vc >> 6, dd = vc & 63;
        int row0 = m0 + wr * 64 + m * 16 + lg * 4;
        int bb = row0 >> 11, t0 = row0 & 2047;
        size_t vrow = (size_t)((bb * 16 + hh) * 64 + dd);
        int slot = (t0 >> 6) * 64 + pv_perm(t0 & 63);
        ushort4 o;
        o.x = f2bf(acc[m][n][0]); o.y = f2bf(acc[m][n][1]);
        o.z = f2bf(acc[m][n][2]); o.w = f2bf(acc[m][n][3]);
        *(ushort4*)&vt[vrow * 2048 + slot] = o;
      }
  }
}

// ---------- flash attention: KVBLK=128, 4 warps, paired 64-row bands, dbuf LDS ----------
// grid (bh=32, pr=16). Block processes bands pr and 31-pr (uniform 17 tile-visits).
// Warp w owns rows band*64 + w*16 + lr. 128-key tiles; NT = band/2 + 1.
#define KSTR 72    // Ks row stride (64 d + 8 pad)
#define VSTR 136   // Vs row stride (128 keys + 8 pad)
__global__ __launch_bounds__(256, 2) void attn_kernel(const unsigned short* __restrict__ qg,
                                                      const unsigned short* __restrict__ kvg,
                                                      const unsigned short* __restrict__ vtg,
                                                      const float* __restrict__ biasg,
                                                      const int* __restrict__ tileokg,
                                                      float* __restrict__ outg) {
  const int bh = blockIdx.x, pr = blockIdx.y;
  const int b = bh >> 4, h = bh & 15;
  const int tid = threadIdx.x, w = tid >> 6, l = tid & 63;
  const int lr = l & 15, lg = l >> 4;

  __shared__ unsigned short Ks[2][128 * KSTR];  // [buf][key][d]
  __shared__ unsigned short Vs[2][64 * VSTR];   // [buf][d][permuted key]

  const float QSCALE = 0.125f * 1.44269504089f;  // 1/sqrt(dh) * log2(e)

  for (int bi = 0; bi < 2; ++bi) {
    const int band = bi ? (31 - pr) : pr;   // 64-row band
    const int NT = (band >> 1) + 1;          // 128-key tiles for this band
    const int qrow0 = band * 64 + w * 16;
    const int dlim = (band & 1) * 64 + w * 16 + lr;  // causal limit within diag tile

    // Q fragments for this band
    bf16x8 qf[2];
#pragma unroll
    for (int ks = 0; ks < 2; ++ks) {
      bf16x8 raw = *(const bf16x8*)&qg[(size_t)(b * 2048 + qrow0 + lr) * 1152 + h * 64 + ks * 32 + lg * 8];
#pragma unroll
      for (int j = 0; j < 8; ++j)
        raw[j] = (short)f2bf(bf2f((unsigned short)raw[j]) * QSCALE);
      qf[ks] = raw;
    }

    f32x4 acc[4] = {};
    float m_i = -1e30f, l_part = 0.f;

    // prologue: stage tile 0 into buf 0 (guard: prior band's reads done)
    bf16x8 kreg[4], vreg[4];
#pragma unroll
    for (int it = 0; it < 4; ++it) {
      int slot = it * 256 + tid;
      int krow = slot >> 3, kc8 = (slot & 7) * 8;      // K: 128 rows x 8 chunks
      int vrow = slot >> 4, vc16 = (slot & 15) * 8;    // V: 64 rows x 16 chunks
      kreg[it] = *(const bf16x8*)&kvg[(size_t)(b * 2048 + krow) * 2048 + h * 64 + kc8];
      vreg[it] = *(const bf16x8*)&vtg[((size_t)(bh * 64 + vrow)) * 2048 + vc16];
    }
    __syncthreads();
#pragma unroll
    for (int it = 0; it < 4; ++it) {
      int slot = it * 256 + tid;
      int krow = slot >> 3, kc8 = (slot & 7) * 8;
      int vrow = slot >> 4, vc16 = (slot & 15) * 8;
      *(bf16x8*)&Ks[0][krow * KSTR + kc8] = kreg[it];
      *(bf16x8*)&Vs[0][vrow * VSTR + vc16] = vreg[it];
    }
    __syncthreads();
    int cur = 0;

    for (int kt = 0; kt < NT; ++kt) {
      // prefetch next tile into regs (hides under compute)
      if (kt + 1 < NT) {
#pragma unroll
        for (int it = 0; it < 4; ++it) {
          int slot = it * 256 + tid;
          int krow = slot >> 3, kc8 = (slot & 7) * 8;
          int vrow = slot >> 4, vc16 = (slot & 15) * 8;
          kreg[it] = *(const bf16x8*)&kvg[(size_t)(b * 2048 + (kt + 1) * 128 + krow) * 2048 + h * 64 + kc8];
          vreg[it] = *(const bf16x8*)&vtg[((size_t)(bh * 64 + vrow)) * 2048 + (kt + 1) * 128 + vc16];
        }
      }

      const bool diag = (kt == NT - 1);

      // S^T = K Q^T from Ks[cur]: 8 n-frags x 2 ks
      f32x4 s[8];
      __builtin_amdgcn_s_setprio(1);
#pragma unroll
      for (int n = 0; n < 8; ++n) {
        bf16x8 kf0 = *(const bf16x8*)&Ks[cur][(n * 16 + lr) * KSTR + lg * 8];
        bf16x8 kf1 = *(const bf16x8*)&Ks[cur][(n * 16 + lr) * KSTR + 32 + lg * 8];
        f32x4 z = {};
        z = __builtin_amdgcn_mfma_f32_16x16x32_bf16(kf0, qf[0], z, 0, 0, 0);
        z = __builtin_amdgcn_mfma_f32_16x16x32_bf16(kf1, qf[1], z, 0, 0, 0);
        s[n] = z;
      }
      __builtin_amdgcn_s_setprio(0);

      const int tok = tileokg[b * 32 + 2 * kt] & tileokg[b * 32 + 2 * kt + 1];
      float mx = -1e30f;
      if (tok) {
        if (diag) {
#pragma unroll
          for (int n = 0; n < 8; ++n)
#pragma unroll
            for (int i = 0; i < 4; ++i) {
              float v = (n * 16 + lg * 4 + i <= dlim) ? s[n][i] : -1e30f;
              s[n][i] = v;
              mx = fmaxf(mx, v);
            }
        } else {
#pragma unroll
          for (int n = 0; n < 8; ++n)
#pragma unroll
            for (int i = 0; i < 4; ++i)
              mx = fmaxf(mx, s[n][i]);
        }
      } else {  // rare general-mask path
#pragma unroll
        for (int n = 0; n < 8; ++n)
#pragma unroll
          for (int i = 0; i < 4; ++i) {
            int keyl = n * 16 + lg * 4 + i;
            float v = s[n][i] + biasg[b * 2048 + kt * 128 + keyl];
            if (diag) v = (keyl <= dlim) ? v : -1e30f;
            s[n][i] = v;
            mx = fmaxf(mx, v);
          }
      }
      mx = fmaxf(mx, __shfl_xor(mx, 16, 64));
      mx = fmaxf(mx, __shfl_xor(mx, 32, 64));

      // T13 defer-rescale (THR=8 in log2 domain)
      if (__any(mx - m_i > 8.0f)) {
        float mn = fmaxf(m_i, mx);
        float sc = fexp2(m_i - mn);
        m_i = mn;
        l_part *= sc;
        float scb[4];
#pragma unroll
        for (int i = 0; i < 4; ++i) scb[i] = __shfl(sc, lg * 4 + i, 64);
#pragma unroll
        for (int dt = 0; dt < 4; ++dt)
#pragma unroll
          for (int i = 0; i < 4; ++i) acc[dt][i] *= scb[i];
      }

      float rs = 0.f;
#pragma unroll
      for (int n = 0; n < 8; ++n)
#pragma unroll
        for (int i = 0; i < 4; ++i) {
          float e = fexp2(s[n][i] - m_i);
          s[n][i] = e;
          rs += e;
        }
      l_part += rs;

      // P -> PV A-fragments in registers (V pre-permuted by pv_perm per 64-sub-tile)
      unsigned pk[8][2];
#pragma unroll
      for (int n = 0; n < 8; ++n) {
        asm("v_cvt_pk_bf16_f32 %0, %1, %2" : "=v"(pk[n][0]) : "v"(s[n][0]), "v"(s[n][1]));
        asm("v_cvt_pk_bf16_f32 %0, %1, %2" : "=v"(pk[n][1]) : "v"(s[n][2]), "v"(s[n][3]));
      }
      bf16x8 paf[4];
#pragma unroll
      for (int ks = 0; ks < 4; ++ks) {
        u32x4 uv;
        uv[0] = pk[2 * ks][0];
        uv[1] = pk[2 * ks][1];
        uv[2] = pk[2 * ks + 1][0];
        uv[3] = pk[2 * ks + 1][1];
        paf[ks] = __builtin_bit_cast(bf16x8, uv);
      }

      // O += P V from Vs[cur]: 4 ks x 4 dt
      __builtin_amdgcn_s_setprio(1);
#pragma unroll
      for (int ks = 0; ks < 4; ++ks)
#pragma unroll
        for (int dt = 0; dt < 4; ++dt) {
          bf16x8 vf = *(const bf16x8*)&Vs[cur][(dt * 16 + lr) * VSTR + ks * 32 + lg * 8];
          acc[dt] = __builtin_amdgcn_mfma_f32_16x16x32_bf16(paf[ks], vf, acc[dt], 0, 0, 0);
        }
      __builtin_amdgcn_s_setprio(0);

      // write next tile into the other buffer; single barrier per tile
      if (kt + 1 < NT) {
#pragma unroll
        for (int it = 0; it < 4; ++it) {
          int slot = it * 256 + tid;
          int krow = slot >> 3, kc8 = (slot & 7) * 8;
          int vrow = slot >> 4, vc16 = (slot & 15) * 8;
          *(bf16x8*)&Ks[cur ^ 1][krow * KSTR + kc8] = kreg[it];
          *(bf16x8*)&Vs[cur ^ 1][vrow * VSTR + vc16] = vreg[it];
        }
        __syncthreads();
        cur ^= 1;
      }
    }

    // epilogue: finish l reduction, normalize, store this band
    float lt = l_part;
    lt += __shfl_xor(lt, 16, 64);
    lt += __shfl_xor(lt, 32, 64);
    float inv = 1.f / lt;
    float invb[4];
#pragma unroll
    for (int i = 0; i < 4; ++i) invb[i] = __shfl(inv, lg * 4 + i, 64);
#pragma unroll
    for (int dt = 0; dt < 4; ++dt)
#pragma unroll
      for (int i = 0; i < 4; ++i)
        outg[(size_t)(b * 2048 + qrow0 + lg * 4 + i) * 1024 + h * 64 + dt * 16 + lr] =
            acc[dt][i] * invb[i];
  }
}

// ---------- launch ----------
extern "C" void kernel_launch(void* const* d_in, const int* in_sizes, int n_in,
                              void* d_out, int out_size, void* d_ws, size_t ws_size,
                              hipStream_t stream) {
  const float* x    = (const float*)d_in[0];
  const int*   mask = (const int*)d_in[1];
  const float* w_q  = (const float*)d_in[2];
  const float* w_d  = (const float*)d_in[3];
  const float* w_k  = (const float*)d_in[4];
  const float* w_v  = (const float*)d_in[5];
  float* out = (float*)d_out;

  char* ws = (char*)d_ws;
  size_t off = 0;
  auto alloc = [&](size_t elems) {
    unsigned short* p = (unsigned short*)(ws + off);
    off += ((elems * 2 + 255) & ~(size_t)255);
    return p;
  };
  unsigned short* x_bf = alloc(4194304);      // [4096][1024]
  unsigned short* wqdt = alloc(1152 * 1024);  // [1152][1024]
  unsigned short* wkvt = alloc(2048 * 128);   // [2048][128]
  unsigned short* qlat = alloc(4096 * 1152);  // [4096][1152]: q | latent
  unsigned short* kv   = alloc(4096 * 2048);  // [4096][2048]: K in cols 0..1023
  unsigned short* vt   = alloc(4194304);      // [32][64][2048], pv_perm'd
  float* bias = (float*)alloc(8192);          // 4096 floats
  int* tileok = (int*)alloc(128);             // 64 ints

  prep_kernel<<<2448, 256, 0, stream>>>(x, mask, w_q, w_d, w_k, w_v, x_bf, wqdt, wkvt, bias, tileok);

  gemm_q<<<dim3(32, 18), 256, 0, stream>>>(x_bf, wqdt, qlat);
  gemm_kv<<<dim3(32, 16), 256, 0, stream>>>(qlat + 1024, wkvt, kv, vt);

  attn_kernel<<<dim3(32, 16), 256, 0, stream>>>(qlat, kv, vt, bias, tileok, out);
}